// Round 1
// baseline (518.059 us; speedup 1.0000x reference)
//
#include <hip/hip_runtime.h>
#include <hip/hip_bf16.h>

#define NN 2048
#define MLPW 16

// ---------------- K1: edge MLP -> A (unnormalized, +I), dr = rsqrt(rowsum) ----
__global__ void __launch_bounds__(256) edge_kernel(
    const float* __restrict__ adj, const float* __restrict__ xdeg,
    const float* __restrict__ ydeg,
    const float* __restrict__ Wm1, const float* __restrict__ bm1,
    const float* __restrict__ Wm2, const float* __restrict__ bm2,
    float* __restrict__ A, float* __restrict__ dr) {
  __shared__ float w1[48], b1[16], w2[32], b2s[2];
  __shared__ float wsum[4];
  const int tid = threadIdx.x;
  if (tid < 48) w1[tid] = Wm1[tid];
  if (tid < 16) b1[tid] = bm1[tid];
  if (tid < 32) w2[tid] = Wm2[tid];
  if (tid < 2) b2s[tid] = bm2[tid];
  __syncthreads();
  const int i = blockIdx.x;
  const float4* adj4 = (const float4*)(adj + (size_t)i * NN);
  const float4* xd4 = (const float4*)(xdeg + (size_t)i * NN);
  const float4* yd4 = (const float4*)(ydeg + (size_t)i * NN);
  float4* A4 = (float4*)(A + (size_t)i * NN);
  float rsum = 0.f;
  for (int j4 = tid; j4 < NN / 4; j4 += 256) {
    float4 av = adj4[j4], xv = xd4[j4], yv = yd4[j4];
    float aa[4] = {av.x, av.y, av.z, av.w};
    float xx[4] = {xv.x, xv.y, xv.z, xv.w};
    float yy[4] = {yv.x, yv.y, yv.z, yv.w};
    float oo[4];
#pragma unroll
    for (int e = 0; e < 4; e++) {
      float l0 = b2s[0], l1 = b2s[1];
#pragma unroll
      for (int k = 0; k < MLPW; k++) {
        float h = fmaf(aa[e], w1[k], fmaf(xx[e], w1[16 + k], fmaf(yy[e], w1[32 + k], b1[k])));
        h = fmaxf(h, 0.f);
        l0 = fmaf(h, w2[2 * k], l0);
        l1 = fmaf(h, w2[2 * k + 1], l1);
      }
      // softmax(axis=-1)[...,1] == sigmoid(l1 - l0)
      float mask = 1.f / (1.f + __expf(l0 - l1));
      float v = aa[e] * mask;
      int j = j4 * 4 + e;
      if (j == i) v += 1.f;
      oo[e] = v;
      rsum += v;
    }
    A4[j4] = make_float4(oo[0], oo[1], oo[2], oo[3]);
  }
#pragma unroll
  for (int off = 32; off > 0; off >>= 1) rsum += __shfl_down(rsum, off);
  if ((tid & 63) == 0) wsum[tid >> 6] = rsum;
  __syncthreads();
  if (tid == 0) {
    float t = wsum[0] + wsum[1] + wsum[2] + wsum[3];
    dr[i] = t > 0.f ? rsqrtf(t) : 0.f;
  }
}

// ---------------- K2: column-sum partials (coalesced, no atomics) -------------
__global__ void __launch_bounds__(256) colsum_partial_kernel(
    const float* __restrict__ A, float* __restrict__ partial) {
  const int j = blockIdx.x * 256 + threadIdx.x;
  const int i0 = blockIdx.y * (NN / 32);
  float s = 0.f;
  for (int i = i0; i < i0 + NN / 32; i++) s += A[(size_t)i * NN + j];
  partial[(size_t)blockIdx.y * NN + j] = s;
}

// ---------------- K3: dc = rsqrt(colsum) --------------------------------------
__global__ void __launch_bounds__(256) dc_kernel(
    const float* __restrict__ partial, float* __restrict__ dc) {
  const int j = blockIdx.x * 256 + threadIdx.x;
  float s = 0.f;
#pragma unroll
  for (int p = 0; p < 32; p++) s += partial[(size_t)p * NN + j];
  dc[j] = s > 0.f ? rsqrtf(s) : 0.f;
}

// ---------------- LDS-tiled fp32 GEMM: C = rowScale[i] * (A@B) + bias[j] ------
template <int BM, int BN, int BK, int TM, int TN>
__global__ void __launch_bounds__(256) sgemm_kernel(
    const float* __restrict__ A, const float* __restrict__ B, float* __restrict__ C,
    int M, int N, int K, const float* __restrict__ rowScale,
    const float* __restrict__ bias) {
  constexpr int TX = BN / TN;  // threads along N
  __shared__ float As[BK][BM + 4];  // +4 pad: store phase stride-BK conflict fix
  __shared__ float Bs[BK][BN];
  const int tid = threadIdx.x;
  const int tx = tid % TX, ty = tid / TX;
  const int row0 = blockIdx.y * BM;
  const int col0 = blockIdx.x * BN;
  float acc[TM][TN];
#pragma unroll
  for (int m = 0; m < TM; m++)
#pragma unroll
    for (int n = 0; n < TN; n++) acc[m][n] = 0.f;

  for (int k0 = 0; k0 < K; k0 += BK) {
    for (int e = tid; e < BM * BK; e += 256) {
      int m = e / BK, k = e % BK;
      As[k][m] = A[(size_t)(row0 + m) * K + k0 + k];
    }
    for (int e = tid; e < BK * BN; e += 256) {
      int kr = e / BN, n = e % BN;
      Bs[kr][n] = B[(size_t)(k0 + kr) * N + col0 + n];
    }
    __syncthreads();
#pragma unroll
    for (int kk = 0; kk < BK; kk++) {
      float a[TM], b[TN];
#pragma unroll
      for (int m = 0; m < TM; m++) a[m] = As[kk][ty * TM + m];
#pragma unroll
      for (int n = 0; n < TN; n++) b[n] = Bs[kk][tx * TN + n];
#pragma unroll
      for (int m = 0; m < TM; m++)
#pragma unroll
        for (int n = 0; n < TN; n++) acc[m][n] = fmaf(a[m], b[n], acc[m][n]);
    }
    __syncthreads();
  }
#pragma unroll
  for (int m = 0; m < TM; m++) {
    int row = row0 + ty * TM + m;
    float rs = rowScale ? rowScale[row] : 1.f;
#pragma unroll
    for (int n = 0; n < TN; n++) {
      int col = col0 + tx * TN + n;
      float bi = bias ? bias[col] : 0.f;
      C[(size_t)row * N + col] = fmaf(acc[m][n], rs, bi);
    }
  }
}

// ---------------- K7: HW[j,c] = dc[j] * (hid[j,:] @ Wg2[:,c]) -----------------
__global__ void __launch_bounds__(256) hw_kernel(
    const float* __restrict__ hid, const float* __restrict__ Wg2,
    const float* __restrict__ dc, float* __restrict__ HW) {
  __shared__ float w[256];
  const int tid = threadIdx.x;
  w[tid] = Wg2[tid];
  __syncthreads();
  const int j = blockIdx.x * 64 + (tid >> 2);
  const int c = tid & 3;
  const float* hrow = hid + (size_t)j * 64;
  float s = 0.f;
#pragma unroll
  for (int f = 0; f < 64; f++) s = fmaf(hrow[f], w[f * 4 + c], s);
  HW[(size_t)j * 4 + c] = dc[j] * s;
}

// ---------------- K8: out[i,:] = dr[i] * (A[i,:] @ HW) ------------------------
__global__ void __launch_bounds__(256) out_kernel(
    const float* __restrict__ A, const float* __restrict__ HW,
    const float* __restrict__ dr, float* __restrict__ outp) {
  const int i = blockIdx.x, tid = threadIdx.x;
  const float* arow = A + (size_t)i * NN;
  const float4* hw4 = (const float4*)HW;
  float ax = 0.f, ay = 0.f, az = 0.f, aw = 0.f;
  for (int j = tid; j < NN; j += 256) {
    float a = arow[j];
    float4 h = hw4[j];
    ax = fmaf(a, h.x, ax);
    ay = fmaf(a, h.y, ay);
    az = fmaf(a, h.z, az);
    aw = fmaf(a, h.w, aw);
  }
  __shared__ float red[4][256];
  red[0][tid] = ax; red[1][tid] = ay; red[2][tid] = az; red[3][tid] = aw;
  __syncthreads();
  for (int s = 128; s > 0; s >>= 1) {
    if (tid < s) {
      red[0][tid] += red[0][tid + s];
      red[1][tid] += red[1][tid + s];
      red[2][tid] += red[2][tid + s];
      red[3][tid] += red[3][tid + s];
    }
    __syncthreads();
  }
  if (tid < 4) outp[(size_t)i * 4 + tid] = dr[i] * red[tid][0];
}

extern "C" void kernel_launch(void* const* d_in, const int* in_sizes, int n_in,
                              void* d_out, int out_size, void* d_ws, size_t ws_size,
                              hipStream_t stream) {
  const float* x    = (const float*)d_in[0];
  const float* adj  = (const float*)d_in[1];
  const float* xdeg = (const float*)d_in[2];
  const float* ydeg = (const float*)d_in[3];
  const float* Wm1  = (const float*)d_in[4];
  const float* bm1  = (const float*)d_in[5];
  const float* Wm2  = (const float*)d_in[6];
  const float* bm2  = (const float*)d_in[7];
  const float* Wg1  = (const float*)d_in[8];
  const float* Wl2  = (const float*)d_in[9];
  const float* bl2  = (const float*)d_in[10];
  const float* Wg2  = (const float*)d_in[11];

  char* ws = (char*)d_ws;
  float* A    = (float*)(ws);                 // 2048*2048 f32 = 16 MiB
  float* XW   = (float*)(ws + 16777216);      // 2048*256  f32 =  2 MiB
  float* T1   = (float*)(ws + 18874368);      // 2048*256  f32 =  2 MiB
  float* part = (float*)(ws + 20971520);      // 32*2048   f32
  float* dr   = (float*)(ws + 21233664);      // 2048
  float* dc   = (float*)(ws + 21241856);      // 2048
  float* HW   = (float*)(ws + 21250048);      // 2048*4

  float* outp = (float*)d_out;                // output 0: [2048,4]
  float* hid  = (float*)d_out + 2048 * 4;     // output 1: [2048,64]

  // A (unnormalized, +I) and dr
  edge_kernel<<<NN, 256, 0, stream>>>(adj, xdeg, ydeg, Wm1, bm1, Wm2, bm2, A, dr);
  // colsum -> dc
  colsum_partial_kernel<<<dim3(NN / 256, 32), 256, 0, stream>>>(A, part);
  dc_kernel<<<NN / 256, 256, 0, stream>>>(part, dc);
  // XW = (x @ Wg1) * dc[row]
  sgemm_kernel<32, 64, 16, 2, 4><<<dim3(256 / 64, 2048 / 32), 256, 0, stream>>>(
      x, Wg1, XW, 2048, 256, 1024, dc, nullptr);
  // T1 = (A @ XW) * dr[row]
  sgemm_kernel<32, 64, 16, 2, 4><<<dim3(256 / 64, 2048 / 32), 256, 0, stream>>>(
      A, XW, T1, 2048, 256, 2048, dr, nullptr);
  // hid = T1 @ Wl2 + bl2   (written straight into d_out slot 1)
  sgemm_kernel<32, 64, 16, 2, 4><<<dim3(64 / 64, 2048 / 32), 256, 0, stream>>>(
      T1, Wl2, hid, 2048, 64, 256, nullptr, bl2);
  // HW = dc[row] * (hid @ Wg2)
  hw_kernel<<<NN / 64, 256, 0, stream>>>(hid, Wg2, dc, HW);
  // out = dr[row] * (A @ HW)
  out_kernel<<<NN, 256, 0, stream>>>(A, HW, dr, outp);
}

// Round 2
// 246.815 us; speedup vs baseline: 2.0990x; 2.0990x over previous
//
#include <hip/hip_runtime.h>

#define NN 2048
#define MLPW 16

typedef __attribute__((ext_vector_type(8))) short short8v;
typedef __attribute__((ext_vector_type(4))) float float4v;
typedef __attribute__((ext_vector_type(4))) unsigned short ushort4v;
typedef __attribute__((ext_vector_type(8))) unsigned short ushort8v;

__device__ __forceinline__ unsigned short f2b(float f) {
  unsigned int u = __float_as_uint(f);
  unsigned int r = (u + 0x7fffu + ((u >> 16) & 1u)) >> 16;  // RNE
  return (unsigned short)r;
}
__device__ __forceinline__ float b2f(unsigned short u) {
  return __uint_as_float(((unsigned int)u) << 16);
}

// ---------------- K0: prep — xb = bf16(x); Wg1T = bf16(Wg1^T) -----------------
__global__ void __launch_bounds__(256) prep_kernel(
    const float* __restrict__ x, const float* __restrict__ Wg1,
    unsigned short* __restrict__ xb, unsigned short* __restrict__ wT) {
  const int b = blockIdx.x, tid = threadIdx.x;
  if (b < 2048) {
    const float4* xr = (const float4*)(x + (size_t)b * 1024);
    ushort4v* o = (ushort4v*)(xb + (size_t)b * 1024);
    float4 v = xr[tid];
    ushort4v p = {f2b(v.x), f2b(v.y), f2b(v.z), f2b(v.w)};
    o[tid] = p;
  } else {
    const int n = b - 2048;  // 0..255
    for (int k = tid; k < 1024; k += 256)
      wT[(size_t)n * 1024 + k] = f2b(Wg1[(size_t)k * 256 + n]);
  }
}

// ---------------- K1: edge MLP -> Abf16 (unnormalized, +I), dr ---------------
__global__ void __launch_bounds__(256) edge_kernel(
    const float* __restrict__ adj, const float* __restrict__ xdeg,
    const float* __restrict__ ydeg,
    const float* __restrict__ Wm1, const float* __restrict__ bm1,
    const float* __restrict__ Wm2, const float* __restrict__ bm2,
    unsigned short* __restrict__ Abf, float* __restrict__ dr) {
  __shared__ float w1[48], b1[16], w2[32], b2s[2];
  __shared__ float wsum[4];
  const int tid = threadIdx.x;
  if (tid < 48) w1[tid] = Wm1[tid];
  if (tid < 16) b1[tid] = bm1[tid];
  if (tid < 32) w2[tid] = Wm2[tid];
  if (tid < 2) b2s[tid] = bm2[tid];
  __syncthreads();
  const int i = blockIdx.x;
  const float4* adj4 = (const float4*)(adj + (size_t)i * NN);
  const float4* xd4 = (const float4*)(xdeg + (size_t)i * NN);
  const float4* yd4 = (const float4*)(ydeg + (size_t)i * NN);
  ushort4v* A4 = (ushort4v*)(Abf + (size_t)i * NN);
  float rsum = 0.f;
  for (int j4 = tid; j4 < NN / 4; j4 += 256) {
    float4 av = adj4[j4], xv = xd4[j4], yv = yd4[j4];
    float aa[4] = {av.x, av.y, av.z, av.w};
    float xx[4] = {xv.x, xv.y, xv.z, xv.w};
    float yy[4] = {yv.x, yv.y, yv.z, yv.w};
    ushort4v oo;
#pragma unroll
    for (int e = 0; e < 4; e++) {
      float l0 = b2s[0], l1 = b2s[1];
#pragma unroll
      for (int k = 0; k < MLPW; k++) {
        float h = fmaf(aa[e], w1[k], fmaf(xx[e], w1[16 + k], fmaf(yy[e], w1[32 + k], b1[k])));
        h = fmaxf(h, 0.f);
        l0 = fmaf(h, w2[2 * k], l0);
        l1 = fmaf(h, w2[2 * k + 1], l1);
      }
      float mask = 1.f / (1.f + __expf(l0 - l1));  // softmax[...,1]
      float v = aa[e] * mask;
      int j = j4 * 4 + e;
      if (j == i) v += 1.f;
      oo[e] = f2b(v);
      rsum += v;
    }
    A4[j4] = oo;
  }
#pragma unroll
  for (int off = 32; off > 0; off >>= 1) rsum += __shfl_down(rsum, off);
  if ((tid & 63) == 0) wsum[tid >> 6] = rsum;
  __syncthreads();
  if (tid == 0) {
    float t = wsum[0] + wsum[1] + wsum[2] + wsum[3];
    dr[i] = t > 0.f ? rsqrtf(t) : 0.f;
  }
}

// ---------------- K2/K3: colsum -> dc ----------------------------------------
__global__ void __launch_bounds__(256) colsum_partial_kernel(
    const unsigned short* __restrict__ Abf, float* __restrict__ partial) {
  const int j = blockIdx.x * 256 + threadIdx.x;
  const int i0 = blockIdx.y * (NN / 32);
  float s = 0.f;
  for (int i = i0; i < i0 + NN / 32; i++) s += b2f(Abf[(size_t)i * NN + j]);
  partial[(size_t)blockIdx.y * NN + j] = s;
}

__global__ void __launch_bounds__(256) dc_kernel(
    const float* __restrict__ partial, float* __restrict__ dc) {
  const int j = blockIdx.x * 256 + threadIdx.x;
  float s = 0.f;
#pragma unroll
  for (int p = 0; p < 32; p++) s += partial[(size_t)p * NN + j];
  dc[j] = s > 0.f ? rsqrtf(s) : 0.f;
}

// ---------------- MFMA bf16 GEMM --------------------------------------------
// C[M,N] = A[M,K] @ BT[N,K]^T.  Output either:
//   Cf  (fp32 [M,N], scaled by scaleM[row])          when Cf  != nullptr
//   CTb (bf16 [N,M] transposed, scaled by scaleM[m]) when CTb != nullptr
// Tiles: block 64x64, BK=64, 4 waves of 32x32 (2x2 mfma_16x16x32 tiles).
__global__ void __launch_bounds__(256) gemm_mfma_kernel(
    const unsigned short* __restrict__ A, const unsigned short* __restrict__ BT,
    int M, int N, int K,
    float* __restrict__ Cf, unsigned short* __restrict__ CTb,
    const float* __restrict__ scaleM) {
  __shared__ unsigned short As[64][72];  // +8 pad: 2-way-max bank aliasing
  __shared__ unsigned short Bs[64][72];
  const int tid = threadIdx.x;
  const int lane = tid & 63, wave = tid >> 6;
  const int l15 = lane & 15, quad = lane >> 4;
  const int mbase = (wave & 1) * 32, nbase = (wave >> 1) * 32;
  const int row0 = blockIdx.y * 64, col0 = blockIdx.x * 64;

  float4v acc[2][2];
#pragma unroll
  for (int a = 0; a < 2; a++)
#pragma unroll
    for (int b = 0; b < 2; b++) acc[a][b] = {0.f, 0.f, 0.f, 0.f};

  for (int k0 = 0; k0 < K; k0 += 64) {
    // stage A tile (64 rows x 64 k, 16B chunks; 512 chunks / 256 threads)
#pragma unroll
    for (int c = tid; c < 512; c += 256) {
      int r = c >> 3, kc = (c & 7) * 8;
      *(ushort8v*)&As[r][kc] = *(const ushort8v*)&A[(size_t)(row0 + r) * K + k0 + kc];
    }
#pragma unroll
    for (int c = tid; c < 512; c += 256) {
      int r = c >> 3, kc = (c & 7) * 8;
      *(ushort8v*)&Bs[r][kc] = *(const ushort8v*)&BT[(size_t)(col0 + r) * K + k0 + kc];
    }
    __syncthreads();
#pragma unroll
    for (int kk = 0; kk < 64; kk += 32) {
      short8v a[2], b[2];
#pragma unroll
      for (int mi = 0; mi < 2; mi++)
        a[mi] = *(const short8v*)&As[mbase + mi * 16 + l15][kk + quad * 8];
#pragma unroll
      for (int ni = 0; ni < 2; ni++)
        b[ni] = *(const short8v*)&Bs[nbase + ni * 16 + l15][kk + quad * 8];
#pragma unroll
      for (int mi = 0; mi < 2; mi++)
#pragma unroll
        for (int ni = 0; ni < 2; ni++)
          acc[mi][ni] = __builtin_amdgcn_mfma_f32_16x16x32_bf16(a[mi], b[ni], acc[mi][ni], 0, 0, 0);
    }
    __syncthreads();
  }

  // epilogue — C/D frag: row = quad*4 + i, col = l15
#pragma unroll
  for (int mi = 0; mi < 2; mi++) {
    const int mg = row0 + mbase + mi * 16 + quad * 4;  // 4-aligned
    const float4 sc = *(const float4*)&scaleM[mg];
    const float s4[4] = {sc.x, sc.y, sc.z, sc.w};
#pragma unroll
    for (int ni = 0; ni < 2; ni++) {
      const int ng = col0 + nbase + ni * 16 + l15;
      if (Cf) {
#pragma unroll
        for (int i = 0; i < 4; i++)
          Cf[(size_t)(mg + i) * N + ng] = acc[mi][ni][i] * s4[i];
      } else {
        ushort4v p = {f2b(acc[mi][ni][0] * s4[0]), f2b(acc[mi][ni][1] * s4[1]),
                      f2b(acc[mi][ni][2] * s4[2]), f2b(acc[mi][ni][3] * s4[3])};
        *(ushort4v*)&CTb[(size_t)ng * M + mg] = p;
      }
    }
  }
}

// ---------------- fp32 tiled GEMM (small, kept for T1@Wl2+bl2) ---------------
template <int BM, int BN, int BK, int TM, int TN>
__global__ void __launch_bounds__(256) sgemm_kernel(
    const float* __restrict__ A, const float* __restrict__ B, float* __restrict__ C,
    int M, int N, int K, const float* __restrict__ rowScale,
    const float* __restrict__ bias) {
  constexpr int TX = BN / TN;
  __shared__ float As[BK][BM + 4];
  __shared__ float Bs[BK][BN];
  const int tid = threadIdx.x;
  const int tx = tid % TX, ty = tid / TX;
  const int row0 = blockIdx.y * BM;
  const int col0 = blockIdx.x * BN;
  float acc[TM][TN];
#pragma unroll
  for (int m = 0; m < TM; m++)
#pragma unroll
    for (int n = 0; n < TN; n++) acc[m][n] = 0.f;
  for (int k0 = 0; k0 < K; k0 += BK) {
    for (int e = tid; e < BM * BK; e += 256) {
      int m = e / BK, k = e % BK;
      As[k][m] = A[(size_t)(row0 + m) * K + k0 + k];
    }
    for (int e = tid; e < BK * BN; e += 256) {
      int kr = e / BN, n = e % BN;
      Bs[kr][n] = B[(size_t)(k0 + kr) * N + col0 + n];
    }
    __syncthreads();
#pragma unroll
    for (int kk = 0; kk < BK; kk++) {
      float a[TM], b[TN];
#pragma unroll
      for (int m = 0; m < TM; m++) a[m] = As[kk][ty * TM + m];
#pragma unroll
      for (int n = 0; n < TN; n++) b[n] = Bs[kk][tx * TN + n];
#pragma unroll
      for (int m = 0; m < TM; m++)
#pragma unroll
        for (int n = 0; n < TN; n++) acc[m][n] = fmaf(a[m], b[n], acc[m][n]);
    }
    __syncthreads();
  }
#pragma unroll
  for (int m = 0; m < TM; m++) {
    int row = row0 + ty * TM + m;
    float rs = rowScale ? rowScale[row] : 1.f;
#pragma unroll
    for (int n = 0; n < TN; n++) {
      int col = col0 + tx * TN + n;
      float bi = bias ? bias[col] : 0.f;
      C[(size_t)row * N + col] = fmaf(acc[m][n], rs, bi);
    }
  }
}

// ---------------- K7: HW[j,c] = dc[j] * (hid[j,:] @ Wg2[:,c]) ----------------
__global__ void __launch_bounds__(256) hw_kernel(
    const float* __restrict__ hid, const float* __restrict__ Wg2,
    const float* __restrict__ dc, float* __restrict__ HW) {
  __shared__ float w[256];
  const int tid = threadIdx.x;
  w[tid] = Wg2[tid];
  __syncthreads();
  const int j = blockIdx.x * 64 + (tid >> 2);
  const int c = tid & 3;
  const float* hrow = hid + (size_t)j * 64;
  float s = 0.f;
#pragma unroll
  for (int f = 0; f < 64; f++) s = fmaf(hrow[f], w[f * 4 + c], s);
  HW[(size_t)j * 4 + c] = dc[j] * s;
}

// ---------------- K8: out[i,:] = dr[i] * (Abf[i,:] @ HW) ---------------------
__global__ void __launch_bounds__(256) out_kernel(
    const unsigned short* __restrict__ Abf, const float* __restrict__ HW,
    const float* __restrict__ dr, float* __restrict__ outp) {
  const int i = blockIdx.x, tid = threadIdx.x;
  const ushort8v a8 = ((const ushort8v*)(Abf + (size_t)i * NN))[tid];
  const float4* hw4 = (const float4*)HW;
  const int j0 = tid * 8;
  float ax = 0.f, ay = 0.f, az = 0.f, aw = 0.f;
#pragma unroll
  for (int e = 0; e < 8; e++) {
    float a = b2f(a8[e]);
    float4 h = hw4[j0 + e];
    ax = fmaf(a, h.x, ax);
    ay = fmaf(a, h.y, ay);
    az = fmaf(a, h.z, az);
    aw = fmaf(a, h.w, aw);
  }
  __shared__ float red[4][256];
  red[0][tid] = ax; red[1][tid] = ay; red[2][tid] = az; red[3][tid] = aw;
  __syncthreads();
  for (int s = 128; s > 0; s >>= 1) {
    if (tid < s) {
      red[0][tid] += red[0][tid + s];
      red[1][tid] += red[1][tid + s];
      red[2][tid] += red[2][tid + s];
      red[3][tid] += red[3][tid + s];
    }
    __syncthreads();
  }
  if (tid < 4) outp[(size_t)i * 4 + tid] = dr[i] * red[tid][0];
}

extern "C" void kernel_launch(void* const* d_in, const int* in_sizes, int n_in,
                              void* d_out, int out_size, void* d_ws, size_t ws_size,
                              hipStream_t stream) {
  const float* x    = (const float*)d_in[0];
  const float* adj  = (const float*)d_in[1];
  const float* xdeg = (const float*)d_in[2];
  const float* ydeg = (const float*)d_in[3];
  const float* Wm1  = (const float*)d_in[4];
  const float* bm1  = (const float*)d_in[5];
  const float* Wm2  = (const float*)d_in[6];
  const float* bm2  = (const float*)d_in[7];
  const float* Wg1  = (const float*)d_in[8];
  const float* Wl2  = (const float*)d_in[9];
  const float* bl2  = (const float*)d_in[10];
  const float* Wg2  = (const float*)d_in[11];

  char* ws = (char*)d_ws;
  unsigned short* Abf  = (unsigned short*)(ws);              // 8 MiB
  unsigned short* XWT  = (unsigned short*)(ws + 8388608);    // 1 MiB  [256][2048]
  unsigned short* xb   = (unsigned short*)(ws + 9437184);    // 4 MiB  [2048][1024]
  unsigned short* Wg1T = (unsigned short*)(ws + 13631488);   // 0.5 MiB [256][1024]
  float* T1   = (float*)(ws + 14155776);                     // 2 MiB  [2048][256]
  float* part = (float*)(ws + 16252928);                     // 256 KiB
  float* dr   = (float*)(ws + 16515072);
  float* dc   = (float*)(ws + 16523264);
  float* HW   = (float*)(ws + 16531456);

  float* outp = (float*)d_out;             // output 0: [2048,4]
  float* hid  = (float*)d_out + 2048 * 4;  // output 1: [2048,64]

  prep_kernel<<<2048 + 256, 256, 0, stream>>>(x, Wg1, xb, Wg1T);
  edge_kernel<<<NN, 256, 0, stream>>>(adj, xdeg, ydeg, Wm1, bm1, Wm2, bm2, Abf, dr);
  colsum_partial_kernel<<<dim3(NN / 256, 32), 256, 0, stream>>>(Abf, part);
  dc_kernel<<<NN / 256, 256, 0, stream>>>(part, dc);
  // XWT[n][m] = dc[m] * (x @ Wg1)[m][n]   (bf16, transposed out)
  gemm_mfma_kernel<<<dim3(256 / 64, 2048 / 64), 256, 0, stream>>>(
      xb, Wg1T, 2048, 256, 1024, nullptr, XWT, dc);
  // T1[m][n] = dr[m] * sum_k A[m][k] * XWT[n][k]
  gemm_mfma_kernel<<<dim3(256 / 64, 2048 / 64), 256, 0, stream>>>(
      Abf, XWT, 2048, 256, 2048, T1, nullptr, dr);
  // hid = T1 @ Wl2 + bl2  (fp32, straight into d_out slot 1)
  sgemm_kernel<32, 64, 16, 2, 4><<<dim3(64 / 64, 2048 / 32), 256, 0, stream>>>(
      T1, Wl2, hid, 2048, 64, 256, nullptr, bl2);
  hw_kernel<<<NN / 64, 256, 0, stream>>>(hid, Wg2, dc, HW);
  out_kernel<<<NN, 256, 0, stream>>>(Abf, HW, dr, outp);
}

// Round 3
// 179.047 us; speedup vs baseline: 2.8934x; 1.3785x over previous
//
#include <hip/hip_runtime.h>

#define NN 2048
#define MLPW 16

typedef __attribute__((ext_vector_type(8))) short short8v;
typedef __attribute__((ext_vector_type(16))) float float16v;
typedef __attribute__((ext_vector_type(4))) unsigned short ushort4v;
typedef __attribute__((ext_vector_type(8))) unsigned short ushort8v;

__device__ __forceinline__ unsigned short f2b(float f) {
  unsigned int u = __float_as_uint(f);
  unsigned int r = (u + 0x7fffu + ((u >> 16) & 1u)) >> 16;  // RNE
  return (unsigned short)r;
}
__device__ __forceinline__ float b2f(unsigned short u) {
  return __uint_as_float(((unsigned int)u) << 16);
}

// ---------------- K0: Wg1T[n][k] = bf16(Wg1[k][n]) ---------------------------
__global__ void __launch_bounds__(256) prep_wT_kernel(
    const float* __restrict__ Wg1, unsigned short* __restrict__ wT) {
  const int n = blockIdx.x, tid = threadIdx.x;
  for (int k = tid; k < 1024; k += 256)
    wT[(size_t)n * 1024 + k] = f2b(Wg1[(size_t)k * 256 + n]);
}

// ---------------- K1: edge MLP -> Abf16 (unnormalized, +I), dr ---------------
__global__ void __launch_bounds__(256) edge_kernel(
    const float* __restrict__ adj, const float* __restrict__ xdeg,
    const float* __restrict__ ydeg,
    const float* __restrict__ Wm1, const float* __restrict__ bm1,
    const float* __restrict__ Wm2, const float* __restrict__ bm2,
    unsigned short* __restrict__ Abf, float* __restrict__ dr) {
  __shared__ float w1[48], b1[16], w2[32], b2s[2];
  __shared__ float wsum[4];
  const int tid = threadIdx.x;
  if (tid < 48) w1[tid] = Wm1[tid];
  if (tid < 16) b1[tid] = bm1[tid];
  if (tid < 32) w2[tid] = Wm2[tid];
  if (tid < 2) b2s[tid] = bm2[tid];
  __syncthreads();
  const int i = blockIdx.x;
  const float4* adj4 = (const float4*)(adj + (size_t)i * NN);
  const float4* xd4 = (const float4*)(xdeg + (size_t)i * NN);
  const float4* yd4 = (const float4*)(ydeg + (size_t)i * NN);
  ushort4v* A4 = (ushort4v*)(Abf + (size_t)i * NN);
  float rsum = 0.f;
  for (int j4 = tid; j4 < NN / 4; j4 += 256) {
    float4 av = adj4[j4], xv = xd4[j4], yv = yd4[j4];
    float aa[4] = {av.x, av.y, av.z, av.w};
    float xx[4] = {xv.x, xv.y, xv.z, xv.w};
    float yy[4] = {yv.x, yv.y, yv.z, yv.w};
    ushort4v oo;
#pragma unroll
    for (int e = 0; e < 4; e++) {
      float l0 = b2s[0], l1 = b2s[1];
#pragma unroll
      for (int k = 0; k < MLPW; k++) {
        float h = fmaf(aa[e], w1[k], fmaf(xx[e], w1[16 + k], fmaf(yy[e], w1[32 + k], b1[k])));
        h = fmaxf(h, 0.f);
        l0 = fmaf(h, w2[2 * k], l0);
        l1 = fmaf(h, w2[2 * k + 1], l1);
      }
      float mask = 1.f / (1.f + __expf(l0 - l1));  // softmax[...,1]
      float v = aa[e] * mask;
      int j = j4 * 4 + e;
      if (j == i) v += 1.f;
      oo[e] = f2b(v);
      rsum += v;
    }
    A4[j4] = oo;
  }
#pragma unroll
  for (int off = 32; off > 0; off >>= 1) rsum += __shfl_down(rsum, off);
  if ((tid & 63) == 0) wsum[tid >> 6] = rsum;
  __syncthreads();
  if (tid == 0) {
    float t = wsum[0] + wsum[1] + wsum[2] + wsum[3];
    dr[i] = t > 0.f ? rsqrtf(t) : 0.f;
  }
}

// ---------------- K2/K3: colsum -> dc ----------------------------------------
__global__ void __launch_bounds__(256) colsum_partial_kernel(
    const unsigned short* __restrict__ Abf, float* __restrict__ partial) {
  const int j = blockIdx.x * 256 + threadIdx.x;
  const int i0 = blockIdx.y * (NN / 32);
  float s = 0.f;
  for (int i = i0; i < i0 + NN / 32; i++) s += b2f(Abf[(size_t)i * NN + j]);
  partial[(size_t)blockIdx.y * NN + j] = s;
}

__global__ void __launch_bounds__(256) dc_kernel(
    const float* __restrict__ partial, float* __restrict__ dc) {
  const int j = blockIdx.x * 256 + threadIdx.x;
  float s = 0.f;
#pragma unroll
  for (int p = 0; p < 32; p++) s += partial[(size_t)p * NN + j];
  dc[j] = s > 0.f ? rsqrtf(s) : 0.f;
}

// ---------------- split-K MFMA GEMM ------------------------------------------
// P[sk][m][n] = sum_{k in chunk sk} A[m][k] * B[n][k]
// A bf16 [M][K]; B either bf16 [N][K] or fp32 [N][K] (converted during staging).
// Block: BM=32 x BN=128, BK=64; 4 waves, one 32x32 mfma tile each.
template <bool B_F32>
__global__ void __launch_bounds__(256) gemm_splitk_kernel(
    const unsigned short* __restrict__ A, const void* __restrict__ Bv,
    float* __restrict__ P, int M, int N, int K, int Kc) {
  __shared__ unsigned short As[32 * 80];   // stride 80 ushorts = 160 B (16B-aligned, uniform banks)
  __shared__ unsigned short Bs[128 * 80];
  const int tid = threadIdx.x;
  const int lane = tid & 63, wave = tid >> 6;
  const int l31 = lane & 31, half = lane >> 5;
  const int row0 = blockIdx.y * 32, col0 = blockIdx.x * 128;
  const int kbeg = blockIdx.z * Kc;

  float16v acc;
#pragma unroll
  for (int r = 0; r < 16; r++) acc[r] = 0.f;

  for (int k0 = 0; k0 < Kc; k0 += 64) {
    // stage A: 32x64 = 256 16B-chunks, one per thread
    {
      const int r = tid >> 3, c = tid & 7;
      *(ushort8v*)&As[r * 80 + c * 8] =
          *(const ushort8v*)&A[(size_t)(row0 + r) * K + kbeg + k0 + c * 8];
    }
    // stage B: 128x64 = 1024 chunks, 4 per thread
#pragma unroll
    for (int i = 0; i < 4; i++) {
      const int id = tid + i * 256;
      const int r = id >> 3, c = id & 7;
      if (B_F32) {
        const float* bp = (const float*)Bv + (size_t)(col0 + r) * K + kbeg + k0 + c * 8;
        float4 u = *(const float4*)bp, v = *(const float4*)(bp + 4);
        ushort8v pk = {f2b(u.x), f2b(u.y), f2b(u.z), f2b(u.w),
                       f2b(v.x), f2b(v.y), f2b(v.z), f2b(v.w)};
        *(ushort8v*)&Bs[r * 80 + c * 8] = pk;
      } else {
        *(ushort8v*)&Bs[r * 80 + c * 8] =
            *(const ushort8v*)&((const unsigned short*)Bv)[(size_t)(col0 + r) * K + kbeg + k0 + c * 8];
      }
    }
    __syncthreads();
    // A frag: m=lane&31, k=(lane>>5)*8+j ; B frag: n=lane&31, same k
#pragma unroll
    for (int ks = 0; ks < 4; ks++) {
      short8v a = *(const short8v*)&As[l31 * 80 + ks * 16 + half * 8];
      short8v b = *(const short8v*)&Bs[(wave * 32 + l31) * 80 + ks * 16 + half * 8];
      acc = __builtin_amdgcn_mfma_f32_32x32x16_bf16(a, b, acc, 0, 0, 0);
    }
    __syncthreads();
  }
  // C/D: col = lane&31, row = (reg&3) + 8*(reg>>2) + 4*(lane>>5)
  float* Pb = P + ((size_t)blockIdx.z * M + row0) * N + col0 + wave * 32 + l31;
#pragma unroll
  for (int reg = 0; reg < 16; reg++) {
    const int m = (reg & 3) + 8 * (reg >> 2) + 4 * half;
    Pb[(size_t)m * N] = acc[reg];
  }
}

// ---------------- reduce GEMM1 partials -> XWT bf16 [256][2048], *dc[col] ----
__global__ void __launch_bounds__(256) reduce_xwt_kernel(
    const float* __restrict__ P, const float* __restrict__ dc,
    unsigned short* __restrict__ XWT) {
  const int t = blockIdx.x * 256 + threadIdx.x;
  const int i = t >> 8;            // output row (0..255)
  const int j0 = (t & 255) * 8;    // output col group (0..2040)
  float s[8] = {0, 0, 0, 0, 0, 0, 0, 0};
#pragma unroll
  for (int sk = 0; sk < 4; sk++) {
    const float* p = P + ((size_t)sk * 256 + i) * 2048 + j0;
    float4 u = *(const float4*)p, v = *(const float4*)(p + 4);
    s[0] += u.x; s[1] += u.y; s[2] += u.z; s[3] += u.w;
    s[4] += v.x; s[5] += v.y; s[6] += v.z; s[7] += v.w;
  }
  float4 d0 = *(const float4*)&dc[j0], d1 = *(const float4*)&dc[j0 + 4];
  ushort8v o = {f2b(s[0] * d0.x), f2b(s[1] * d0.y), f2b(s[2] * d0.z), f2b(s[3] * d0.w),
                f2b(s[4] * d1.x), f2b(s[5] * d1.y), f2b(s[6] * d1.z), f2b(s[7] * d1.w)};
  *(ushort8v*)&XWT[(size_t)i * 2048 + j0] = o;
}

// ---------------- fused tail: P2 -> T1(=dr*sum) -> hid(@Wl2+bl2) -> HW(@Wg2*dc)
__global__ void __launch_bounds__(256) tail_kernel(
    const float* __restrict__ P2, const float* __restrict__ dr,
    const float* __restrict__ dc, const float* __restrict__ Wl2,
    const float* __restrict__ bl2, const float* __restrict__ Wg2,
    float* __restrict__ hid, float* __restrict__ HW) {
  __shared__ float T1s[16][256];
  __shared__ float hidS[16][68];
  const int m0 = blockIdx.x * 16;
  const int tid = threadIdx.x;
  // phase 1: T1 rows (reduce split-K partials, scale by dr)
#pragma unroll
  for (int i = 0; i < 16; i++) {
    const int idx = tid + i * 256;
    const int mi = idx >> 8, n = idx & 255;
    float s = 0.f;
#pragma unroll
    for (int sk = 0; sk < 4; sk++)
      s += P2[((size_t)sk * 2048 + m0 + mi) * 256 + n];
    T1s[mi][n] = s * dr[m0 + mi];
  }
  __syncthreads();
  // phase 2: hid[m][j] = T1[m][:] @ Wl2[:,j] + bl2[j]
  const int j = tid & 63, mg = tid >> 6;  // wave handles rows mg*4..mg*4+3
  float h[4] = {bl2[j], bl2[j], bl2[j], bl2[j]};
  for (int n = 0; n < 256; n++) {
    float w = Wl2[(size_t)n * 64 + j];
#pragma unroll
    for (int r = 0; r < 4; r++) h[r] = fmaf(T1s[mg * 4 + r][n], w, h[r]);
  }
#pragma unroll
  for (int r = 0; r < 4; r++) {
    hid[(size_t)(m0 + mg * 4 + r) * 64 + j] = h[r];
    hidS[mg * 4 + r][j] = h[r];
  }
  __syncthreads();
  // phase 3: HW[m][c] = dc[m] * hid[m][:] @ Wg2[:,c]
  if (tid < 64) {
    const int r = tid >> 2, c = tid & 3;
    float s = 0.f;
#pragma unroll
    for (int jj = 0; jj < 64; jj++) s = fmaf(hidS[r][jj], Wg2[jj * 4 + c], s);
    HW[(size_t)(m0 + r) * 4 + c] = s * dc[m0 + r];
  }
}

// ---------------- out[i,:] = dr[i] * (Abf[i,:] @ HW) -------------------------
__global__ void __launch_bounds__(256) out_kernel(
    const unsigned short* __restrict__ Abf, const float* __restrict__ HW,
    const float* __restrict__ dr, float* __restrict__ outp) {
  const int i = blockIdx.x, tid = threadIdx.x;
  const ushort8v a8 = ((const ushort8v*)(Abf + (size_t)i * NN))[tid];
  const float4* hw4 = (const float4*)HW;
  const int j0 = tid * 8;
  float ax = 0.f, ay = 0.f, az = 0.f, aw = 0.f;
#pragma unroll
  for (int e = 0; e < 8; e++) {
    float a = b2f(a8[e]);
    float4 h = hw4[j0 + e];
    ax = fmaf(a, h.x, ax);
    ay = fmaf(a, h.y, ay);
    az = fmaf(a, h.z, az);
    aw = fmaf(a, h.w, aw);
  }
  __shared__ float red[4][256];
  red[0][tid] = ax; red[1][tid] = ay; red[2][tid] = az; red[3][tid] = aw;
  __syncthreads();
  for (int s = 128; s > 0; s >>= 1) {
    if (tid < s) {
      red[0][tid] += red[0][tid + s];
      red[1][tid] += red[1][tid + s];
      red[2][tid] += red[2][tid + s];
      red[3][tid] += red[3][tid + s];
    }
    __syncthreads();
  }
  if (tid < 4) outp[(size_t)i * 4 + tid] = dr[i] * red[tid][0];
}

extern "C" void kernel_launch(void* const* d_in, const int* in_sizes, int n_in,
                              void* d_out, int out_size, void* d_ws, size_t ws_size,
                              hipStream_t stream) {
  const float* x    = (const float*)d_in[0];
  const float* adj  = (const float*)d_in[1];
  const float* xdeg = (const float*)d_in[2];
  const float* ydeg = (const float*)d_in[3];
  const float* Wm1  = (const float*)d_in[4];
  const float* bm1  = (const float*)d_in[5];
  const float* Wm2  = (const float*)d_in[6];
  const float* bm2  = (const float*)d_in[7];
  const float* Wg1  = (const float*)d_in[8];
  const float* Wl2  = (const float*)d_in[9];
  const float* bl2  = (const float*)d_in[10];
  const float* Wg2  = (const float*)d_in[11];

  char* ws = (char*)d_ws;
  unsigned short* Abf  = (unsigned short*)(ws);              // 8 MiB [2048][2048]
  unsigned short* Wg1T = (unsigned short*)(ws + 8388608);    // 0.5 MiB [256][1024]
  unsigned short* XWT  = (unsigned short*)(ws + 8912896);    // 1 MiB [256][2048]
  float* P    = (float*)(ws + 9961472);                      // 8 MiB  split-K partials
  float* part = (float*)(ws + 18350080);                     // 256 KiB
  float* dr   = (float*)(ws + 18612224);
  float* dc   = (float*)(ws + 18620416);
  float* HW   = (float*)(ws + 18628608);                     // 32 KiB

  float* outp = (float*)d_out;             // output 0: [2048,4]
  float* hid  = (float*)d_out + 2048 * 4;  // output 1: [2048,64]

  prep_wT_kernel<<<256, 256, 0, stream>>>(Wg1, Wg1T);
  edge_kernel<<<NN, 256, 0, stream>>>(adj, xdeg, ydeg, Wm1, bm1, Wm2, bm2, Abf, dr);
  colsum_partial_kernel<<<dim3(NN / 256, 32), 256, 0, stream>>>(Abf, part);
  dc_kernel<<<NN / 256, 256, 0, stream>>>(part, dc);
  // GEMM1 (role-swapped): P[sk][i][j] partial of Wg1T @ x^T  (M=256, N=2048, K=1024)
  gemm_splitk_kernel<true><<<dim3(2048 / 128, 256 / 32, 4), 256, 0, stream>>>(
      Wg1T, x, P, 256, 2048, 1024, 256);
  reduce_xwt_kernel<<<256, 256, 0, stream>>>(P, dc, XWT);
  // GEMM2: P[sk][m][n] partial of Abf @ XWT^T  (M=2048, N=256, K=2048)
  gemm_splitk_kernel<false><<<dim3(256 / 128, 2048 / 32, 4), 256, 0, stream>>>(
      Abf, XWT, P, 2048, 256, 2048, 512);
  // tail: reduce + dr scale -> hid (d_out) and HW (= dc * hid @ Wg2)
  tail_kernel<<<2048 / 16, 256, 0, stream>>>(P, dr, dc, Wl2, bl2, Wg2, hid, HW);
  out_kernel<<<NN, 256, 0, stream>>>(Abf, HW, dr, outp);
}